// Round 12
// baseline (77.094 us; speedup 1.0000x reference)
//
#include <hip/hip_runtime.h>
#include <hip/hip_bf16.h>
#include <cstdint>
#include <cmath>

#define NT 4096      // tokens
#define DIN 512      // input dim
#define DOUT 1280    // total output dim
#define NE 8         // experts
#define TDIM 64      // type-embedding dim
#define MAXTILES 80  // sum_g ceil(cnt_g/128) <= 4096*2/128 + 16 = 80
#define NB 10        // DOUT / 128 n-blocks
#define GATE_BLOCKS (NT / 4)                    // 1024
#define CONVW_BLOCKS (20 * (DIN / 64) * NE)     // 1280

typedef __attribute__((ext_vector_type(8))) short bhalf8;
typedef __attribute__((ext_vector_type(4))) float f32x4;

__device__ __forceinline__ unsigned short f2bf(float f) {
    __hip_bfloat16 h = __float2bfloat16(f);
    return *reinterpret_cast<unsigned short*>(&h);
}

// async global->LDS, 16B per lane. LDS dest = wave-uniform base + lane*16.
__device__ __forceinline__ void glds16(const unsigned short* g, unsigned short* l) {
    __builtin_amdgcn_global_load_lds(
        (const __attribute__((address_space(1))) void*)g,
        (__attribute__((address_space(3))) void*)l, 16, 0, 0);
}

// ---------------------------------------------------------------------------
// K1: fused prep. Gate blocks: gating (fp32) + x->bf16. Convw blocks:
// W_exp [e][k][n] -> WT [e][n][k] bf16 via LDS transpose.
// ---------------------------------------------------------------------------
__global__ __launch_bounds__(256) void prep_kernel(
    const float* __restrict__ x, const float* __restrict__ temb,
    const int* __restrict__ atype, const float* __restrict__ Wg,
    const float* __restrict__ W,
    unsigned short* __restrict__ xb, unsigned short* __restrict__ WT,
    int* __restrict__ e0a, int* __restrict__ e1a,
    float* __restrict__ g0a, float* __restrict__ g1a)
{
    __shared__ unsigned short t[64 * 72];
    const int tid = threadIdx.x;

    if ((int)blockIdx.x < GATE_BLOCKS) {
        const int n = blockIdx.x * 4 + (tid >> 6);
        const int l = tid & 63;

        float acc[NE];
#pragma unroll
        for (int e = 0; e < NE; ++e) acc[e] = 0.f;

        const float* xr = x + (size_t)n * DIN;
#pragma unroll
        for (int i = 0; i < DIN / 64; ++i) {
            const int k = i * 64 + l;
            const float xv = xr[k];
            xb[(size_t)n * DIN + k] = f2bf(xv);
            const float* wr = Wg + (size_t)k * NE;
#pragma unroll
            for (int e = 0; e < NE; ++e) acc[e] = fmaf(xv, wr[e], acc[e]);
        }
        {
            const int tt = atype[n];
            const float tv = temb[(size_t)tt * TDIM + l];
            const float* wr = Wg + (size_t)(DIN + l) * NE;
#pragma unroll
            for (int e = 0; e < NE; ++e) acc[e] = fmaf(tv, wr[e], acc[e]);
        }
#pragma unroll
        for (int off = 32; off > 0; off >>= 1) {
#pragma unroll
            for (int e = 0; e < NE; ++e) acc[e] += __shfl_xor(acc[e], off, 64);
        }
        if (l == 0) {
            int e0 = 0; float v0 = acc[0];
#pragma unroll
            for (int e = 1; e < NE; ++e) if (acc[e] > v0) { v0 = acc[e]; e0 = e; }
            int e1 = -1; float v1 = -INFINITY;
#pragma unroll
            for (int e = 0; e < NE; ++e) {
                if (e == e0) continue;
                if (acc[e] > v1) { v1 = acc[e]; e1 = e; }
            }
            const float p1 = expf(v1 - v0);
            const float s  = 1.f + p1;
            e0a[n] = e0; e1a[n] = e1; g0a[n] = 1.f / s; g1a[n] = p1 / s;
        }
    } else {
        const int b  = blockIdx.x - GATE_BLOCKS;
        const int n0 = (b % 20) * 64;
        const int k0 = ((b / 20) % (DIN / 64)) * 64;
        const int e  = b / (20 * (DIN / 64));
        const int nl = tid & 63;
        const int kb = tid >> 6;
#pragma unroll
        for (int r = 0; r < 16; ++r) {
            const int kl = r * 4 + kb;
            t[nl * 72 + kl] = f2bf(W[((size_t)e * DIN + k0 + kl) * DOUT + n0 + nl]);
        }
        __syncthreads();
        const int nw = tid >> 2;
        const int kc = tid & 3;
        uint4* dst = reinterpret_cast<uint4*>(
            WT + ((size_t)e * DOUT + n0 + nw) * DIN + k0 + kc * 16);
        const uint4* src = reinterpret_cast<const uint4*>(&t[nw * 72 + kc * 16]);
        dst[0] = src[0];
        dst[1] = src[1];
    }
}

// ---------------------------------------------------------------------------
// K2: counting sort -> padded grouped layout. tile_group[t] = g in [0,16)
// (slot = g>>3, expert = g&7). meta2[0] = ntiles.
// ---------------------------------------------------------------------------
#define SORT_T 1024
__global__ __launch_bounds__(1024) void sort_kernel(
    const int* __restrict__ e0a, const int* __restrict__ e1a,
    const float* __restrict__ g0a, const float* __restrict__ g1a,
    int* __restrict__ perm, float* __restrict__ pgate,
    int* __restrict__ tile_group, int* __restrict__ meta2)
{
    __shared__ int hist[16 * SORT_T];     // 64 KB
    __shared__ int gtot[16], gbase[16];
    const int t = threadIdx.x;
    for (int i = t; i < MAXTILES * 128; i += SORT_T) { perm[i] = 0; pgate[i] = 0.f; }
#pragma unroll
    for (int g = 0; g < 16; ++g) hist[g * SORT_T + t] = 0;
    __syncthreads();

    const int nbase = t * 4;
    int keys[8];
#pragma unroll
    for (int i = 0; i < 4; ++i) {
        const int n = nbase + i;
        keys[2 * i]     = e0a[n];
        keys[2 * i + 1] = 8 + e1a[n];
    }
#pragma unroll
    for (int i = 0; i < 8; ++i) hist[keys[i] * SORT_T + t] += 1;
    __syncthreads();

    const int w = t >> 6, l = t & 63;
    {
        int running = 0;
        for (int c = 0; c < SORT_T / 64; ++c) {
            int v = hist[w * SORT_T + c * 64 + l];
            int inc = v;
#pragma unroll
            for (int d = 1; d < 64; d <<= 1) {
                int u = __shfl_up(inc, d, 64);
                if (l >= d) inc += u;
            }
            hist[w * SORT_T + c * 64 + l] = running + inc - v;
            running += __shfl(inc, 63, 64);
        }
        if (l == 0) gtot[w] = running;
    }
    __syncthreads();
    if (t == 0) {
        int s = 0;
#pragma unroll
        for (int g = 0; g < 16; ++g) {
            gbase[g] = s;
            const int ntg = (gtot[g] + 127) >> 7;
            for (int k = 0; k < ntg; ++k) tile_group[s / 128 + k] = g;
            s += ntg * 128;
        }
        meta2[0] = s / 128;       // ntiles
    }
    __syncthreads();

#pragma unroll
    for (int i = 0; i < 4; ++i) {
        const int n = nbase + i;
        {
            const int k = keys[2 * i];
            const int pos = gbase[k] + hist[k * SORT_T + t]++;
            perm[pos] = n; pgate[pos] = g0a[n];
        }
        {
            const int k = keys[2 * i + 1];
            const int pos = gbase[k] + hist[k * SORT_T + t]++;
            perm[pos] = n; pgate[pos] = g1a[n];
        }
    }
}

// ---------------------------------------------------------------------------
// K3: grouped GEMM — 128x128 tile, BK=64, 4 waves, proven
// stage->sync->compute->sync loop, glds16 + source-side swizzle, XCD swizzle.
// Two dependent launches (round-2-proven ordering), both atomics-free:
//   PASS 0 (slot-0 tiles): out = g0*(acc+b). Every token is a real row of
//     exactly one slot-0 tile -> every output element stored exactly once.
//     Dummy rows (gate==0) skipped; real slot-0 gate >= 0.5 > 0.
//   PASS 1 (slot-1 tiles): out += g1*(acc+b). Plain read-add-write — each
//     element touched by exactly one thread in this launch; stream-ordered
//     after pass 0. Deterministic.
// ---------------------------------------------------------------------------
__device__ __forceinline__ int swz(int row, int chunk) {
    return row * 64 + ((chunk ^ (row & 7)) << 3);       // elem idx, 16B chunks
}

template<int PASS>
__global__ __launch_bounds__(256, 4) void gemm_kernel(
    const unsigned short* __restrict__ Xb,
    const unsigned short* __restrict__ WT,
    const float* __restrict__ bexp,
    const int* __restrict__ perm, const float* __restrict__ pgate,
    const int* __restrict__ tile_group, const int* __restrict__ meta2,
    float* __restrict__ out)
{
    constexpr int NWG = MAXTILES * NB, CPX = NWG / 8;   // 800, 100
    const int gid = blockIdx.x;
    const int wid = (gid & 7) * CPX + (gid >> 3);
    const int tile = wid / NB, nb = wid % NB;
    if (tile >= meta2[0]) return;
    const int g = tile_group[tile];
    if ((g >> 3) != PASS) return;              // block-uniform slot filter
    const int e  = g & 7;
    const int n0 = nb * 128;

    __shared__ unsigned short As[128 * 64];   // 16 KB
    __shared__ unsigned short Bs[128 * 64];   // 16 KB
    __shared__ int   toks[128];
    __shared__ float gts[128];

    const int tid = threadIdx.x;
    if (tid < 128) {
        toks[tid] = perm[tile * 128 + tid];
        gts[tid]  = pgate[tile * 128 + tid];
    }
    __syncthreads();

    const int l = tid & 63;
    const int w = tid >> 6;
    const int lrow = l >> 3;                  // 0..7 within 8-row stripe
    const int schk = (l & 7) ^ lrow;          // swizzled source 16B chunk

    const unsigned short* asrc[4];
    unsigned short* aldsb[4];
#pragma unroll
    for (int i = 0; i < 4; ++i) {
        asrc[i]  = Xb + (size_t)toks[i * 32 + w * 8 + lrow] * DIN + schk * 8;
        aldsb[i] = &As[(i * 32 + w * 8) * 64];
    }
    const unsigned short* bsrc[4];
    unsigned short* bldsb[4];
#pragma unroll
    for (int j = 0; j < 4; ++j) {
        bsrc[j]  = WT + ((size_t)e * DOUT + n0 + j * 32 + w * 8 + lrow) * DIN + schk * 8;
        bldsb[j] = &Bs[(j * 32 + w * 8) * 64];
    }

    f32x4 acc[4][4];
#pragma unroll
    for (int a = 0; a < 4; ++a)
#pragma unroll
        for (int b = 0; b < 4; ++b) acc[a][b] = (f32x4){0.f, 0.f, 0.f, 0.f};

    const int wm = w >> 1, wn = w & 1;        // 2x2 waves: 64 rows x 64 cols
    const int fr = l & 15;
    const int fh = l >> 4;                    // k chunk within 32-elem half

    for (int k0 = 0; k0 < DIN; k0 += 64) {
        __syncthreads();                      // prev compute done reading LDS
#pragma unroll
        for (int i = 0; i < 4; ++i) glds16(asrc[i] + k0, aldsb[i]);
#pragma unroll
        for (int j = 0; j < 4; ++j) glds16(bsrc[j] + k0, bldsb[j]);
        __syncthreads();                      // drains vmcnt(0): data visible
#pragma unroll
        for (int ks = 0; ks < 2; ++ks) {
            bhalf8 af[4], bff[4];
#pragma unroll
            for (int fm = 0; fm < 4; ++fm)
                af[fm] = *reinterpret_cast<const bhalf8*>(
                    &As[swz(wm * 64 + fm * 16 + fr, ks * 4 + fh)]);
#pragma unroll
            for (int fn = 0; fn < 4; ++fn)
                bff[fn] = *reinterpret_cast<const bhalf8*>(
                    &Bs[swz(wn * 64 + fn * 16 + fr, ks * 4 + fh)]);
#pragma unroll
            for (int fm = 0; fm < 4; ++fm)
#pragma unroll
                for (int fn = 0; fn < 4; ++fn)
                    acc[fm][fn] = __builtin_amdgcn_mfma_f32_16x16x32_bf16(
                        af[fm], bff[fn], acc[fm][fn], 0, 0, 0);
        }
    }

    // ---- epilogue: write split output chunks (PASS0 store / PASS1 RMW)
    size_t base; int width, cstart;
    if (n0 < 512)       { base = 0;                 width = 512; cstart = n0; }
    else if (n0 < 1024) { base = (size_t)NT * 512;  width = 512; cstart = n0 - 512; }
    else                { base = (size_t)NT * 1024; width = 256; cstart = n0 - 1024; }
    const int lc = l & 15, lr = l >> 4;
    const int coloff = cstart + wn * 64 + lc;
    float bval[4];
#pragma unroll
    for (int fn = 0; fn < 4; ++fn)
        bval[fn] = bexp[(size_t)e * DOUT + n0 + wn * 64 + fn * 16 + lc];
#pragma unroll
    for (int fm = 0; fm < 4; ++fm) {
#pragma unroll
        for (int j = 0; j < 4; ++j) {
            const int row = wm * 64 + fm * 16 + lr * 4 + j;
            const float gg = gts[row];
            if (gg != 0.f) {                  // dummy rows have gate 0
                float* op = out + base + (size_t)toks[row] * width + coloff;
#pragma unroll
                for (int fn = 0; fn < 4; ++fn) {
                    const float v = gg * (acc[fm][fn][j] + bval[fn]);
                    if (PASS == 0) op[fn * 16] = v;
                    else           op[fn * 16] += v;
                }
            }
        }
    }
}

// ---------------------------------------------------------------------------
// host launcher
// ---------------------------------------------------------------------------
extern "C" void kernel_launch(void* const* d_in, const int* in_sizes, int n_in,
                              void* d_out, int out_size, void* d_ws, size_t ws_size,
                              hipStream_t stream) {
    const float* x     = (const float*)d_in[0];
    const float* temb  = (const float*)d_in[1];
    const int*   atype = (const int*)d_in[2];
    const float* Wg    = (const float*)d_in[3];
    const float* Wexp  = (const float*)d_in[4];
    const float* bexp  = (const float*)d_in[5];
    float* out = (float*)d_out;
    char*  ws  = (char*)d_ws;

    unsigned short* xb = (unsigned short*)(ws);                        // 4 MB
    unsigned short* wt = (unsigned short*)(ws + (size_t)4194304);      // 10.5 MB
    char* meta = ws + (size_t)14680064;
    int*   e0a = (int*)(meta);
    int*   e1a = (int*)(meta + 16384);
    float* g0a = (float*)(meta + 32768);
    float* g1a = (float*)(meta + 49152);
    int*   perm       = (int*)(meta + 65536);     // 40960 B
    float* pgate      = (float*)(meta + 106496);  // 40960 B
    int*   tile_group = (int*)(meta + 147456);    // 512 B
    int*   meta2      = (int*)(meta + 147968);    // 8 B

    prep_kernel<<<dim3(GATE_BLOCKS + CONVW_BLOCKS), dim3(256), 0, stream>>>(
        x, temb, atype, Wg, Wexp, xb, wt, e0a, e1a, g0a, g1a);
    sort_kernel<<<dim3(1), dim3(SORT_T), 0, stream>>>(
        e0a, e1a, g0a, g1a, perm, pgate, tile_group, meta2);
    gemm_kernel<0><<<dim3(MAXTILES * NB), dim3(256), 0, stream>>>(
        xb, wt, bexp, perm, pgate, tile_group, meta2, out);
    gemm_kernel<1><<<dim3(MAXTILES * NB), dim3(256), 0, stream>>>(
        xb, wt, bexp, perm, pgate, tile_group, meta2, out);
}

// Round 13
// 61.403 us; speedup vs baseline: 1.2555x; 1.2555x over previous
//
#include <hip/hip_runtime.h>
#include <hip/hip_bf16.h>
#include <cstdint>
#include <cmath>

#define NT 4096      // tokens
#define DIN 512      // input dim
#define DOUT 1280    // total output dim
#define NE 8         // experts
#define TDIM 64      // type-embedding dim
#define MAXTILES 80  // sum_g ceil(cnt_g/128) <= 4096*2/128 + 16 = 80
#define NB 10        // DOUT / 128 n-blocks
#define GATE_BLOCKS (NT / 4)                    // 1024
#define CONVW_BLOCKS (20 * (DIN / 64) * NE)     // 1280
#define S1ROWS 5120  // max padded slot-1 rows

typedef __attribute__((ext_vector_type(8))) short bhalf8;
typedef __attribute__((ext_vector_type(8))) unsigned short ushort8;
typedef __attribute__((ext_vector_type(4))) float f32x4;

__device__ __forceinline__ unsigned short f2bf(float f) {
    __hip_bfloat16 h = __float2bfloat16(f);
    return *reinterpret_cast<unsigned short*>(&h);
}
__device__ __forceinline__ float bf2f(unsigned short u) {
    unsigned int v = (unsigned int)u << 16;
    return *reinterpret_cast<float*>(&v);
}

// async global->LDS, 16B per lane. LDS dest = wave-uniform base + lane*16.
__device__ __forceinline__ void glds16(const unsigned short* g, unsigned short* l) {
    __builtin_amdgcn_global_load_lds(
        (const __attribute__((address_space(1))) void*)g,
        (__attribute__((address_space(3))) void*)l, 16, 0, 0);
}

// ---------------------------------------------------------------------------
// K1: fused prep. Gate blocks: gating (fp32) + x->bf16. Convw blocks:
// W_exp [e][k][n] -> WT [e][n][k] bf16 via LDS transpose.
// ---------------------------------------------------------------------------
__global__ __launch_bounds__(256) void prep_kernel(
    const float* __restrict__ x, const float* __restrict__ temb,
    const int* __restrict__ atype, const float* __restrict__ Wg,
    const float* __restrict__ W,
    unsigned short* __restrict__ xb, unsigned short* __restrict__ WT,
    int* __restrict__ e0a, int* __restrict__ e1a,
    float* __restrict__ g0a, float* __restrict__ g1a)
{
    __shared__ unsigned short t[64 * 72];
    const int tid = threadIdx.x;

    if ((int)blockIdx.x < GATE_BLOCKS) {
        const int n = blockIdx.x * 4 + (tid >> 6);
        const int l = tid & 63;

        float acc[NE];
#pragma unroll
        for (int e = 0; e < NE; ++e) acc[e] = 0.f;

        const float* xr = x + (size_t)n * DIN;
#pragma unroll
        for (int i = 0; i < DIN / 64; ++i) {
            const int k = i * 64 + l;
            const float xv = xr[k];
            xb[(size_t)n * DIN + k] = f2bf(xv);
            const float* wr = Wg + (size_t)k * NE;
#pragma unroll
            for (int e = 0; e < NE; ++e) acc[e] = fmaf(xv, wr[e], acc[e]);
        }
        {
            const int tt = atype[n];
            const float tv = temb[(size_t)tt * TDIM + l];
            const float* wr = Wg + (size_t)(DIN + l) * NE;
#pragma unroll
            for (int e = 0; e < NE; ++e) acc[e] = fmaf(tv, wr[e], acc[e]);
        }
#pragma unroll
        for (int off = 32; off > 0; off >>= 1) {
#pragma unroll
            for (int e = 0; e < NE; ++e) acc[e] += __shfl_xor(acc[e], off, 64);
        }
        if (l == 0) {
            int e0 = 0; float v0 = acc[0];
#pragma unroll
            for (int e = 1; e < NE; ++e) if (acc[e] > v0) { v0 = acc[e]; e0 = e; }
            int e1 = -1; float v1 = -INFINITY;
#pragma unroll
            for (int e = 0; e < NE; ++e) {
                if (e == e0) continue;
                if (acc[e] > v1) { v1 = acc[e]; e1 = e; }
            }
            const float p1 = expf(v1 - v0);
            const float s  = 1.f + p1;
            e0a[n] = e0; e1a[n] = e1; g0a[n] = 1.f / s; g1a[n] = p1 / s;
        }
    } else {
        const int b  = blockIdx.x - GATE_BLOCKS;
        const int n0 = (b % 20) * 64;
        const int k0 = ((b / 20) % (DIN / 64)) * 64;
        const int e  = b / (20 * (DIN / 64));
        const int nl = tid & 63;
        const int kb = tid >> 6;
#pragma unroll
        for (int r = 0; r < 16; ++r) {
            const int kl = r * 4 + kb;
            t[nl * 72 + kl] = f2bf(W[((size_t)e * DIN + k0 + kl) * DOUT + n0 + nl]);
        }
        __syncthreads();
        const int nw = tid >> 2;
        const int kc = tid & 3;
        uint4* dst = reinterpret_cast<uint4*>(
            WT + ((size_t)e * DOUT + n0 + nw) * DIN + k0 + kc * 16);
        const uint4* src = reinterpret_cast<const uint4*>(&t[nw * 72 + kc * 16]);
        dst[0] = src[0];
        dst[1] = src[1];
    }
}

// ---------------------------------------------------------------------------
// K2: counting sort -> padded grouped layout. tile_group[t] = g in [0,16).
// Emits ipos1[n] (token n's padded row within slot-1 region) and
// meta2 = {ntiles, slot1_base_row}.
// ---------------------------------------------------------------------------
#define SORT_T 1024
__global__ __launch_bounds__(1024) void sort_kernel(
    const int* __restrict__ e0a, const int* __restrict__ e1a,
    const float* __restrict__ g0a, const float* __restrict__ g1a,
    int* __restrict__ perm, float* __restrict__ pgate,
    int* __restrict__ tile_group, int* __restrict__ ipos1,
    int* __restrict__ meta2)
{
    __shared__ int hist[16 * SORT_T];     // 64 KB
    __shared__ int gtot[16], gbase[16];
    const int t = threadIdx.x;
    for (int i = t; i < MAXTILES * 128; i += SORT_T) { perm[i] = 0; pgate[i] = 0.f; }
#pragma unroll
    for (int g = 0; g < 16; ++g) hist[g * SORT_T + t] = 0;
    __syncthreads();

    const int nbase = t * 4;
    int keys[8];
#pragma unroll
    for (int i = 0; i < 4; ++i) {
        const int n = nbase + i;
        keys[2 * i]     = e0a[n];
        keys[2 * i + 1] = 8 + e1a[n];
    }
#pragma unroll
    for (int i = 0; i < 8; ++i) hist[keys[i] * SORT_T + t] += 1;
    __syncthreads();

    const int w = t >> 6, l = t & 63;
    {
        int running = 0;
        for (int c = 0; c < SORT_T / 64; ++c) {
            int v = hist[w * SORT_T + c * 64 + l];
            int inc = v;
#pragma unroll
            for (int d = 1; d < 64; d <<= 1) {
                int u = __shfl_up(inc, d, 64);
                if (l >= d) inc += u;
            }
            hist[w * SORT_T + c * 64 + l] = running + inc - v;
            running += __shfl(inc, 63, 64);
        }
        if (l == 0) gtot[w] = running;
    }
    __syncthreads();
    if (t == 0) {
        int s = 0;
#pragma unroll
        for (int g = 0; g < 16; ++g) {
            gbase[g] = s;
            const int ntg = (gtot[g] + 127) >> 7;
            for (int k = 0; k < ntg; ++k) tile_group[s / 128 + k] = g;
            s += ntg * 128;
        }
        meta2[0] = s / 128;       // ntiles
        meta2[1] = gbase[8];      // slot-1 base row (padded)
    }
    __syncthreads();

#pragma unroll
    for (int i = 0; i < 4; ++i) {
        const int n = nbase + i;
        {
            const int k = keys[2 * i];
            const int pos = gbase[k] + hist[k * SORT_T + t]++;
            perm[pos] = n; pgate[pos] = g0a[n];
        }
        {
            const int k = keys[2 * i + 1];
            const int pos = gbase[k] + hist[k * SORT_T + t]++;
            perm[pos] = n; pgate[pos] = g1a[n];
            ipos1[n] = pos - gbase[8];
        }
    }
}

// ---------------------------------------------------------------------------
// K3: grouped GEMM — 128x128 tile, BK=64, 4 waves, proven single-buffer
// stage->sync->compute->sync loop, glds16 + source-side swizzle, XCD swizzle.
// NEW: per-tile K-phase stagger (k0 starts at (tile&7)*64, wraps mod 512) —
// desynchronizes the stage/drain windows of different tiles resident on one
// CU so one block's vmcnt(0) drain overlaps another's MFMA. Deterministic
// (order fixed by blockIdx).
// Epilogue: slot-0 plain-stores f32 to out; slot-1 stores bf16 to stage rows.
// ---------------------------------------------------------------------------
__device__ __forceinline__ int swz(int row, int chunk) {
    return row * 64 + ((chunk ^ (row & 7)) << 3);       // elem idx, 16B chunks
}

__global__ __launch_bounds__(256, 4) void gemm_kernel(
    const unsigned short* __restrict__ Xb,
    const unsigned short* __restrict__ WT,
    const float* __restrict__ bexp,
    const int* __restrict__ perm, const float* __restrict__ pgate,
    const int* __restrict__ tile_group, const int* __restrict__ meta2,
    unsigned short* __restrict__ stage, float* __restrict__ out)
{
    constexpr int NWG = MAXTILES * NB, CPX = NWG / 8;   // 800, 100
    const int gid = blockIdx.x;
    const int wid = (gid & 7) * CPX + (gid >> 3);
    const int tile = wid / NB, nb = wid % NB;
    if (tile >= meta2[0]) return;
    const int g  = tile_group[tile];
    const int e  = g & 7;
    const bool s1 = (g >= 8);
    const int n0 = nb * 128;
    const int ph = tile & 7;                  // K-phase stagger

    __shared__ unsigned short As[128 * 64];   // 16 KB
    __shared__ unsigned short Bs[128 * 64];   // 16 KB
    __shared__ int   toks[128];
    __shared__ float gts[128];

    const int tid = threadIdx.x;
    if (tid < 128) {
        toks[tid] = perm[tile * 128 + tid];
        gts[tid]  = pgate[tile * 128 + tid];
    }
    __syncthreads();

    const int l = tid & 63;
    const int w = tid >> 6;
    const int lrow = l >> 3;                  // 0..7 within 8-row stripe
    const int schk = (l & 7) ^ lrow;          // swizzled source 16B chunk

    const unsigned short* asrc[4];
    unsigned short* aldsb[4];
#pragma unroll
    for (int i = 0; i < 4; ++i) {
        asrc[i]  = Xb + (size_t)toks[i * 32 + w * 8 + lrow] * DIN + schk * 8;
        aldsb[i] = &As[(i * 32 + w * 8) * 64];
    }
    const unsigned short* bsrc[4];
    unsigned short* bldsb[4];
#pragma unroll
    for (int j = 0; j < 4; ++j) {
        bsrc[j]  = WT + ((size_t)e * DOUT + n0 + j * 32 + w * 8 + lrow) * DIN + schk * 8;
        bldsb[j] = &Bs[(j * 32 + w * 8) * 64];
    }

    f32x4 acc[4][4];
#pragma unroll
    for (int a = 0; a < 4; ++a)
#pragma unroll
        for (int b = 0; b < 4; ++b) acc[a][b] = (f32x4){0.f, 0.f, 0.f, 0.f};

    const int wm = w >> 1, wn = w & 1;        // 2x2 waves: 64 rows x 64 cols
    const int fr = l & 15;
    const int fh = l >> 4;                    // k chunk within 32-elem half

#pragma unroll
    for (int t = 0; t < DIN / 64; ++t) {
        const int k0 = (((t + ph) & 7)) * 64; // staggered K order (wraps)
        __syncthreads();                      // prev compute done reading LDS
#pragma unroll
        for (int i = 0; i < 4; ++i) glds16(asrc[i] + k0, aldsb[i]);
#pragma unroll
        for (int j = 0; j < 4; ++j) glds16(bsrc[j] + k0, bldsb[j]);
        __syncthreads();                      // drains vmcnt(0): data visible
#pragma unroll
        for (int ks = 0; ks < 2; ++ks) {
            bhalf8 af[4], bff[4];
#pragma unroll
            for (int fm = 0; fm < 4; ++fm)
                af[fm] = *reinterpret_cast<const bhalf8*>(
                    &As[swz(wm * 64 + fm * 16 + fr, ks * 4 + fh)]);
#pragma unroll
            for (int fn = 0; fn < 4; ++fn)
                bff[fn] = *reinterpret_cast<const bhalf8*>(
                    &Bs[swz(wn * 64 + fn * 16 + fr, ks * 4 + fh)]);
#pragma unroll
            for (int fm = 0; fm < 4; ++fm)
#pragma unroll
                for (int fn = 0; fn < 4; ++fn)
                    acc[fm][fn] = __builtin_amdgcn_mfma_f32_16x16x32_bf16(
                        af[fm], bff[fn], acc[fm][fn], 0, 0, 0);
        }
    }

    // ---- epilogue
    const int lc = l & 15, lr = l >> 4;
    float bval[4];
#pragma unroll
    for (int fn = 0; fn < 4; ++fn)
        bval[fn] = bexp[(size_t)e * DOUT + n0 + wn * 64 + fn * 16 + lc];

    if (s1) {
        // slot-1: bf16 stores into stage rows (dummies write their own rows)
        const int srow0 = tile * 128 - meta2[1];
#pragma unroll
        for (int fm = 0; fm < 4; ++fm) {
#pragma unroll
            for (int j = 0; j < 4; ++j) {
                const int row = wm * 64 + fm * 16 + lr * 4 + j;
                const float gg = gts[row];
                unsigned short* sp = stage + (size_t)(srow0 + row) * DOUT + n0 + wn * 64 + lc;
#pragma unroll
                for (int fn = 0; fn < 4; ++fn)
                    sp[fn * 16] = f2bf(gg * (acc[fm][fn][j] + bval[fn]));
            }
        }
    } else {
        size_t base; int width, cstart;
        if (n0 < 512)       { base = 0;                 width = 512; cstart = n0; }
        else if (n0 < 1024) { base = (size_t)NT * 512;  width = 512; cstart = n0 - 512; }
        else                { base = (size_t)NT * 1024; width = 256; cstart = n0 - 1024; }
        const int coloff = cstart + wn * 64 + lc;
#pragma unroll
        for (int fm = 0; fm < 4; ++fm) {
#pragma unroll
            for (int j = 0; j < 4; ++j) {
                const int row = wm * 64 + fm * 16 + lr * 4 + j;
                const float gg = gts[row];
                if (gg != 0.f) {              // dummy rows have gate 0
                    float* op = out + base + (size_t)toks[row] * width + coloff;
#pragma unroll
                    for (int fn = 0; fn < 4; ++fn)
                        op[fn * 16] = gg * (acc[fm][fn][j] + bval[fn]);
                }
            }
        }
    }
}

// ---------------------------------------------------------------------------
// K4: combine — out[n] += bf16(stage[ipos1[n]]). One wave per token,
// ushort8 stage loads + f32x4 out RMW. Each out element touched once.
// ---------------------------------------------------------------------------
__global__ __launch_bounds__(256) void combine_kernel(
    const unsigned short* __restrict__ stage, const int* __restrict__ ipos1,
    float* __restrict__ out)
{
    const int n = blockIdx.x * 4 + (threadIdx.x >> 6);
    const int l = threadIdx.x & 63;
    const ushort8* srow = reinterpret_cast<const ushort8*>(
        stage + (size_t)ipos1[n] * DOUT);
#pragma unroll
    for (int c = l; c < DOUT / 8; c += 64) {   // 160 chunks: 64,64,32
        const ushort8 v8 = srow[c];
        const int col0 = c * 8;
        float* p;
        if (col0 < 512)       p = out + (size_t)n * 512 + col0;
        else if (col0 < 1024) p = out + (size_t)NT * 512 + (size_t)n * 512 + (col0 - 512);
        else                  p = out + (size_t)NT * 1024 + (size_t)n * 256 + (col0 - 1024);
        f32x4* pv = reinterpret_cast<f32x4*>(p);
        f32x4 a0 = pv[0], a1 = pv[1];
#pragma unroll
        for (int j = 0; j < 4; ++j) a0[j] += bf2f(v8[j]);
#pragma unroll
        for (int j = 0; j < 4; ++j) a1[j] += bf2f(v8[4 + j]);
        pv[0] = a0; pv[1] = a1;
    }
}

// ---------------------------------------------------------------------------
// host launcher
// ---------------------------------------------------------------------------
extern "C" void kernel_launch(void* const* d_in, const int* in_sizes, int n_in,
                              void* d_out, int out_size, void* d_ws, size_t ws_size,
                              hipStream_t stream) {
    const float* x     = (const float*)d_in[0];
    const float* temb  = (const float*)d_in[1];
    const int*   atype = (const int*)d_in[2];
    const float* Wg    = (const float*)d_in[3];
    const float* Wexp  = (const float*)d_in[4];
    const float* bexp  = (const float*)d_in[5];
    float* out = (float*)d_out;
    char*  ws  = (char*)d_ws;

    unsigned short* xb = (unsigned short*)(ws);                        // 4 MB
    unsigned short* wt = (unsigned short*)(ws + (size_t)4194304);      // 10.5 MB
    unsigned short* stage = (unsigned short*)(ws + (size_t)14680064);  // 13.1 MB bf16
    const size_t META = 14680064 + (size_t)S1ROWS * DOUT * 2;          // 27787264
    char* meta = ws + META;
    int*   e0a = (int*)(meta);
    int*   e1a = (int*)(meta + 16384);
    float* g0a = (float*)(meta + 32768);
    float* g1a = (float*)(meta + 49152);
    int*   perm       = (int*)(meta + 65536);     // 40960 B
    float* pgate      = (float*)(meta + 106496);  // 40960 B
    int*   tile_group = (int*)(meta + 147456);    // 512 B
    int*   ipos1      = (int*)(meta + 147968);    // 16384 B
    int*   meta2      = (int*)(meta + 164352);    // 8 B

    prep_kernel<<<dim3(GATE_BLOCKS + CONVW_BLOCKS), dim3(256), 0, stream>>>(
        x, temb, atype, Wg, Wexp, xb, wt, e0a, e1a, g0a, g1a);
    sort_kernel<<<dim3(1), dim3(SORT_T), 0, stream>>>(
        e0a, e1a, g0a, g1a, perm, pgate, tile_group, ipos1, meta2);
    gemm_kernel<<<dim3(MAXTILES * NB), dim3(256), 0, stream>>>(
        xb, wt, bexp, perm, pgate, tile_group, meta2, stage, out);
    combine_kernel<<<dim3(NT / 4), dim3(256), 0, stream>>>(stage, ipos1, out);
}